// Round 7
// baseline (244.702 us; speedup 1.0000x reference)
//
#include <hip/hip_runtime.h>
#include <math.h>

#define SIM_T 100

// ---------------------------------------------------------------------------
// Transpose encW [out][in] -> encWT [in][out] so GEMM weight reads are k-major.
// 256KB total, L2-absorbed; ~2us.
// ---------------------------------------------------------------------------
__global__ __launch_bounds__(256) void k_transpose256(
    const float* __restrict__ W, float* __restrict__ WT) {
  int k = blockIdx.x;
  int o = threadIdx.x;
  WT[k * 256 + o] = W[o * 256 + k];
}

// ---------------------------------------------------------------------------
// Permute W2 [256][256] -> W2p so each lane's 4 columns are one contiguous
// float4:  W2p[i*256 + l*4 + q] = W2[i*256 + 64*q + l]
// ---------------------------------------------------------------------------
__global__ __launch_bounds__(256) void k_perm(const float* __restrict__ W2,
                                              float* __restrict__ W2p) {
  int i = blockIdx.x;
  int t = threadIdx.x;
  int l = t >> 2, q = t & 3;
  W2p[i * 256 + t] = W2[i * 256 + q * 64 + l];
}

// ---------------------------------------------------------------------------
// GEMM: O[row][col] = epi( sum_k A[row][k] * WT[k][col] )
// R6 structure ("SV" = streaming, zero-LDS). R5 post-mortem: any both-
// operands-via-LDS tiling is LDS-pipe-bound (12(4+R) LDS-cyc vs 8R VALU-cyc
// per 4k-group) -> ~20us/GEMM floor. Here:
//   - W stream: lane = col-pair, coalesced float2 loads DIRECT from L2
//     (W=256KB L2-resident; 256MB total @34.5TB/s = 7.4us < VALU floor).
//   - A stream: wave-uniform float4 broadcast loads from L1 (block's 16
//     A-rows = 16KB, L1-resident; `zero` arg forces per-lane vector
//     addressing so these CANNOT become strided s_loads - R4's failure).
//   - No LDS, no barriers. Per 4k-group: 12 loads + 64 fma instrs.
// Wave tile: 8 rows x 128 cols. Block: 4 waves = 2 row-groups x 2 col-halves
// (col-half waves share A rows -> L1 hits). Grid 512 = 2 blocks/CU.
// fmaf chain k-ascending per output == R1..R5 exact order (absmax 0).
// EPI 0: sigmoid(acc + bias)   EPI 1: acc * omd
// ---------------------------------------------------------------------------
template <int EPI>
__global__ __launch_bounds__(256, 2) void k_gemm_sv(
    const float* __restrict__ A,     // [8192][256]
    const float* __restrict__ WT,    // [256 k][256 col]
    const float* __restrict__ bias,  // encB (EPI=0) or unused
    float* __restrict__ O,           // [8192][256]
    float omd, int zero) {           // zero == 0 at runtime (opaque)
  const int t = threadIdx.x;
  const int lane = t & 63;
  const int wv = t >> 6;
  const int rg = wv >> 1;  // row group: 8 rows
  const int ch = wv & 1;   // col half: 128 cols
  const int rowbase = blockIdx.x * 16 + rg * 8;
  const int col = ch * 128 + lane * 2;
  // per-lane (VGPR) address, value uniform across lanes -> broadcast load
  const float* Ab = A + (size_t)rowbase * 256 + (lane & zero);
  const float* wp = WT + col;

  float acc[8][2];
#pragma unroll
  for (int r = 0; r < 8; r++) acc[r][0] = acc[r][1] = 0.f;

#pragma unroll 2
  for (int kg = 0; kg < 64; kg++) {
    float2 w0 = *(const float2*)(wp + (kg * 4 + 0) * 256);
    float2 w1 = *(const float2*)(wp + (kg * 4 + 1) * 256);
    float2 w2 = *(const float2*)(wp + (kg * 4 + 2) * 256);
    float2 w3 = *(const float2*)(wp + (kg * 4 + 3) * 256);
    float4 a[8];
#pragma unroll
    for (int r = 0; r < 8; r++)
      a[r] = *(const float4*)(Ab + r * 256 + kg * 4);
#pragma unroll
    for (int r = 0; r < 8; r++) {
      // k ascending: 4kg+0 .. 4kg+3
      acc[r][0] = fmaf(a[r].x, w0.x, acc[r][0]);
      acc[r][1] = fmaf(a[r].x, w0.y, acc[r][1]);
      acc[r][0] = fmaf(a[r].y, w1.x, acc[r][0]);
      acc[r][1] = fmaf(a[r].y, w1.y, acc[r][1]);
      acc[r][0] = fmaf(a[r].z, w2.x, acc[r][0]);
      acc[r][1] = fmaf(a[r].z, w2.y, acc[r][1]);
      acc[r][0] = fmaf(a[r].w, w3.x, acc[r][0]);
      acc[r][1] = fmaf(a[r].w, w3.y, acc[r][1]);
    }
  }

  if (EPI == 0) {
    float2 b = *(const float2*)(bias + col);
#pragma unroll
    for (int r = 0; r < 8; r++) {
      float2 o;
      o.x = 1.f / (1.f + expf(-(acc[r][0] + b.x)));
      o.y = 1.f / (1.f + expf(-(acc[r][1] + b.y)));
      *(float2*)(O + (size_t)(rowbase + r) * 256 + col) = o;
    }
  } else {
#pragma unroll
    for (int r = 0; r < 8; r++) {
      float2 o;
      o.x = __fmul_rn(acc[r][0], omd);
      o.y = __fmul_rn(acc[r][1], omd);
      *(float2*)(O + (size_t)(rowbase + r) * 256 + col) = o;
    }
  }
}

// ---------------------------------------------------------------------------
// Kernel: the 100-step LIF simulation. One wave == one batch row.
// Lane l owns columns {l, 64+l, 128+l, 192+l} of layers 1/2 and column l of
// layer 3. Spike sets via __ballot -> uniform scalar ctz loops; per spike one
// coalesced float4 load of the permuted W2 row.  (unchanged: 76us, VALUBusy
// 80%, VALU-bound at this algorithm's structural floor)
// ---------------------------------------------------------------------------
__global__ __launch_bounds__(256, 8) void k_sim(
    const float* __restrict__ c_in, const float* __restrict__ W2p,
    const float* __restrict__ W3, float* __restrict__ out, float decay,
    float omd) {
  const int lane = threadIdx.x & 63;
  const int row = blockIdx.x * 4 + (threadIdx.x >> 6);
  const float* crow = c_in + (long)row * 256;
  const float c0 = crow[lane];
  const float c1 = crow[64 + lane];
  const float c2 = crow[128 + lane];
  const float c3 = crow[192 + lane];
  float v10 = 0.f, v11 = 0.f, v12 = 0.f, v13 = 0.f;
  float v20 = 0.f, v21 = 0.f, v22 = 0.f, v23 = 0.f;
  float v3 = 0.f;
  int acc = 0;
  const float4* w2p = (const float4*)W2p + lane;  // w2p[i*64] = row i, 4 cols

  for (int t = 0; t < SIM_T; t++) {
    // ---- layer 1 (constant input c) ----
    v10 = __fadd_rn(__fmul_rn(v10, decay), c0);
    bool f0 = v10 >= 1.f;
    unsigned long long m0 = __ballot(f0);
    v10 = f0 ? 0.f : v10;
    v11 = __fadd_rn(__fmul_rn(v11, decay), c1);
    bool f1 = v11 >= 1.f;
    unsigned long long m1 = __ballot(f1);
    v11 = f1 ? 0.f : v11;
    v12 = __fadd_rn(__fmul_rn(v12, decay), c2);
    bool f2 = v12 >= 1.f;
    unsigned long long m2 = __ballot(f2);
    v12 = f2 ? 0.f : v12;
    v13 = __fadd_rn(__fmul_rn(v13, decay), c3);
    bool f3 = v13 >= 1.f;
    unsigned long long m3 = __ballot(f3);
    v13 = f3 ? 0.f : v13;

    // ---- layer 2: syn2 = sum of W2 rows of spiking layer-1 neurons ----
    float s0 = 0.f, s1 = 0.f, s2 = 0.f, s3 = 0.f;
#define ACC2(mask, qb)                            \
  {                                               \
    unsigned long long m = (mask);                \
    while (m) {                                   \
      int i = __builtin_ctzll(m) + (qb);          \
      m &= m - 1;                                 \
      float4 w = w2p[i * 64];                     \
      s0 += w.x;                                  \
      s1 += w.y;                                  \
      s2 += w.z;                                  \
      s3 += w.w;                                  \
    }                                             \
  }
    ACC2(m0, 0)
    ACC2(m1, 64)
    ACC2(m2, 128)
    ACC2(m3, 192)

    v20 = __fadd_rn(__fmul_rn(v20, decay), __fmul_rn(s0, omd));
    bool g0 = v20 >= 1.f;
    unsigned long long n0 = __ballot(g0);
    v20 = g0 ? 0.f : v20;
    v21 = __fadd_rn(__fmul_rn(v21, decay), __fmul_rn(s1, omd));
    bool g1 = v21 >= 1.f;
    unsigned long long n1 = __ballot(g1);
    v21 = g1 ? 0.f : v21;
    v22 = __fadd_rn(__fmul_rn(v22, decay), __fmul_rn(s2, omd));
    bool g2 = v22 >= 1.f;
    unsigned long long n2 = __ballot(g2);
    v22 = g2 ? 0.f : v22;
    v23 = __fadd_rn(__fmul_rn(v23, decay), __fmul_rn(s3, omd));
    bool g3 = v23 >= 1.f;
    unsigned long long n3 = __ballot(g3);
    v23 = g3 ? 0.f : v23;

    // ---- layer 3 (usually no layer-2 spikes: uniform skip) ----
    float z = 0.f;
    if (n0 | n1 | n2 | n3) {
#define ACC3(mask, qb)                            \
  {                                               \
    unsigned long long m = (mask);                \
    while (m) {                                   \
      int i = __builtin_ctzll(m) + (qb);          \
      m &= m - 1;                                 \
      z += W3[i * 64 + lane];                     \
    }                                             \
  }
      ACC3(n0, 0)
      ACC3(n1, 64)
      ACC3(n2, 128)
      ACC3(n3, 192)
    }
    v3 = __fadd_rn(__fmul_rn(v3, decay), __fmul_rn(z, omd));
    bool h = v3 >= 1.f;
    acc += h ? 1 : 0;
    v3 = h ? 0.f : v3;
  }
  out[(long)row * 64 + lane] = __fdiv_rn((float)acc, 100.f);
}

// ---------------------------------------------------------------------------
extern "C" void kernel_launch(void* const* d_in, const int* in_sizes, int n_in,
                              void* d_out, int out_size, void* d_ws,
                              size_t ws_size, hipStream_t stream) {
  const float* x = (const float*)d_in[0];     // [8192,256]
  const float* encW = (const float*)d_in[1];  // [256,256] (out,in)
  const float* encB = (const float*)d_in[2];  // [256]
  const float* W1 = (const float*)d_in[3];    // [256,256] (in,out) k-major
  const float* W2 = (const float*)d_in[4];    // [256,256]
  const float* W3 = (const float*)d_in[5];    // [256,64]
  float* out = (float*)d_out;                 // [8192,64]

  float* c = (float*)d_ws;                        // 8 MB
  float* rates = (float*)d_ws + 2097152;          // 8 MB
  float* W2p = (float*)d_ws + 4194304;            // 256 KB
  float* encWT = (float*)d_ws + 4194304 + 65536;  // 256 KB

  const float decay = (float)exp((double)(-0.05f));
  const float omd = 1.0f - decay;
  const int zero = (int)(ws_size & 0);  // opaque runtime 0

  k_transpose256<<<256, 256, 0, stream>>>(encW, encWT);
  k_perm<<<256, 256, 0, stream>>>(W2, W2p);
  k_gemm_sv<0><<<512, 256, 0, stream>>>(x, encWT, encB, rates, omd, zero);
  k_gemm_sv<1><<<512, 256, 0, stream>>>(rates, W1, encB, c, omd, zero);
  k_sim<<<2048, 256, 0, stream>>>(c, W2p, W3, out, decay, omd);
}